// Round 1
// baseline (9181.862 us; speedup 1.0000x reference)
//
#include <hip/hip_runtime.h>
#include <math.h>

#define NN 100000
#define NE 640000
#define DD 128
#define HH 256
#define NL 3
#define QDIM 768
#define TM 32

// ---------------- q = question_embedding @ qW + qb ----------------
__global__ void q_kernel(const float* __restrict__ qe, const float* __restrict__ qW,
                         const float* __restrict__ qb, float* __restrict__ q) {
    int d = threadIdx.x;  // 128 threads
    float acc = qb[d];
    for (int k = 0; k < QDIM; ++k) acc = fmaf(qe[k], qW[k * DD + d], acc);
    q[d] = acc;
}

// qc[l][h] = eb1[l][h] + sum_d q[d] * eW1[l][3D + d][h]   (q-segment precompute)
__global__ void qc_kernel(const float* __restrict__ q, const float* __restrict__ eW1,
                          const float* __restrict__ eb1, float* __restrict__ qc) {
    int l = blockIdx.x;
    int h = threadIdx.x;  // 256 threads
    const float* W = eW1 + ((size_t)l * 4 * DD + 3 * DD) * HH;
    __shared__ float sq[DD];
    if (h < DD) sq[h] = q[h];
    __syncthreads();
    float acc = eb1[l * HH + h];
    for (int d = 0; d < DD; ++d) acc = fmaf(sq[d], W[d * HH + h], acc);
    qc[l * HH + h] = acc;
}

// ---------------- fused edge MLP + scatter ----------------
// feat = [node_h[src] | node_h[dst] | edge_h | q], h = relu(feat@W1 + b1) (q part in qc)
// edge_h_new = h@W2 + b2 (in place); agg[src] += edge_h_new; agg[dst] += edge_h_new
__global__ __launch_bounds__(256, 2) void edge_kernel(
    const float* __restrict__ node_h, float* __restrict__ edge_h,
    const int* __restrict__ eidx,
    const float* __restrict__ W1,   // [512,256], rows 0..383 used
    const float* __restrict__ qc,   // [256] init (q contrib + b1)
    const float* __restrict__ W2,   // [256,128]
    const float* __restrict__ b2,   // [128]
    float* __restrict__ agg)        // [N,128]
{
    __shared__ float sF[16][36];       // k-subtile of gathered features, transposed
    __shared__ float sW[16 * 256];     // stage A: [16][256]; stage B reuse: [32][128]
    __shared__ float sHt[256][36];     // hidden, transposed [h][row]
    __shared__ int s_src[TM];
    __shared__ int s_dst[TM];
    __shared__ float s_init[HH];
    __shared__ float s_b2[DD];

    const int tid = threadIdx.x;
    const int e0 = blockIdx.x * TM;

    if (tid < TM) {
        s_src[tid] = eidx[e0 + tid];
        s_dst[tid] = eidx[NE + e0 + tid];
    }
    s_init[tid] = qc[tid];
    if (tid < DD) s_b2[tid] = b2[tid];
    __syncthreads();

    const int rg = tid >> 6;          // row group 0..3
    const int r0 = rg * 8;
    const int ct = tid & 63;
    const int c0 = ct * 4;            // stage A col base (256 cols)

    float acc[8][4];
#pragma unroll
    for (int i = 0; i < 8; ++i)
#pragma unroll
        for (int j = 0; j < 4; ++j) acc[i][j] = s_init[c0 + j];

    const int lrow = tid >> 3;        // 0..31  (feature loader)
    const int lkk  = (tid & 7) * 2;   // 0..14
    const int wkk  = tid >> 4;        // 0..15  (W1 loader)
    const int wc   = (tid & 15) * 16;

    for (int seg = 0; seg < 3; ++seg) {
        const float* gbase;
        if (seg == 0)      gbase = node_h + (size_t)s_src[lrow] * DD;
        else if (seg == 1) gbase = node_h + (size_t)s_dst[lrow] * DD;
        else               gbase = edge_h + (size_t)(e0 + lrow) * DD;
        for (int kt = 0; kt < 8; ++kt) {
            const int kb = kt * 16;
            float2 fv = *(const float2*)(gbase + kb + lkk);
            const float* wp = W1 + (size_t)(seg * DD + kb + wkk) * HH + wc;
            float4 w0 = ((const float4*)wp)[0];
            float4 w1 = ((const float4*)wp)[1];
            float4 w2 = ((const float4*)wp)[2];
            float4 w3 = ((const float4*)wp)[3];
            __syncthreads();
            sF[lkk][lrow] = fv.x;
            sF[lkk + 1][lrow] = fv.y;
            float4* wd = (float4*)&sW[wkk * 256 + wc];
            wd[0] = w0; wd[1] = w1; wd[2] = w2; wd[3] = w3;
            __syncthreads();
#pragma unroll
            for (int kk = 0; kk < 16; ++kk) {
                float4 a0 = *(const float4*)&sF[kk][r0];
                float4 a1 = *(const float4*)&sF[kk][r0 + 4];
                float4 b  = *(const float4*)&sW[kk * 256 + c0];
                float av[8] = {a0.x, a0.y, a0.z, a0.w, a1.x, a1.y, a1.z, a1.w};
                float bv[4] = {b.x, b.y, b.z, b.w};
#pragma unroll
                for (int i = 0; i < 8; ++i)
#pragma unroll
                    for (int j = 0; j < 4; ++j)
                        acc[i][j] = fmaf(av[i], bv[j], acc[i][j]);
            }
        }
    }

    // relu -> sHt (transposed)
#pragma unroll
    for (int j = 0; j < 4; ++j)
#pragma unroll
        for (int i = 0; i < 8; ++i)
            sHt[c0 + j][r0 + i] = fmaxf(acc[i][j], 0.0f);

    // ---- stage B: out[32x128] = relu(H) @ W2 + b2 ----
    const int cB = ct * 2;
    float acc2[8][2];
#pragma unroll
    for (int i = 0; i < 8; ++i) { acc2[i][0] = s_b2[cB]; acc2[i][1] = s_b2[cB + 1]; }

    const int bkk = tid >> 3;         // 0..31 (W2 loader)
    const int bc  = (tid & 7) * 16;
    for (int kt = 0; kt < 8; ++kt) {
        const int kb = kt * 32;
        const float* wp = W2 + (size_t)(kb + bkk) * DD + bc;
        float4 w0 = ((const float4*)wp)[0];
        float4 w1 = ((const float4*)wp)[1];
        float4 w2 = ((const float4*)wp)[2];
        float4 w3 = ((const float4*)wp)[3];
        __syncthreads();   // also separates sHt writes (kt=0) / prev sW reads
        float4* wd = (float4*)&sW[bkk * 128 + bc];
        wd[0] = w0; wd[1] = w1; wd[2] = w2; wd[3] = w3;
        __syncthreads();
#pragma unroll
        for (int kk = 0; kk < 32; ++kk) {
            float4 a0 = *(const float4*)&sHt[kb + kk][r0];
            float4 a1 = *(const float4*)&sHt[kb + kk][r0 + 4];
            float2 b  = *(const float2*)&sW[kk * 128 + cB];
            float av[8] = {a0.x, a0.y, a0.z, a0.w, a1.x, a1.y, a1.z, a1.w};
#pragma unroll
            for (int i = 0; i < 8; ++i) {
                acc2[i][0] = fmaf(av[i], b.x, acc2[i][0]);
                acc2[i][1] = fmaf(av[i], b.y, acc2[i][1]);
            }
        }
    }

    // ---- stage C: write edge_h in place + scatter-add ----
#pragma unroll
    for (int i = 0; i < 8; ++i) {
        int r = r0 + i;
        int e = e0 + r;
        float vx = acc2[i][0], vy = acc2[i][1];
        *(float2*)&edge_h[(size_t)e * DD + cB] = make_float2(vx, vy);
        int sn = s_src[r], dn = s_dst[r];
        atomicAdd(&agg[(size_t)sn * DD + cB], vx);
        atomicAdd(&agg[(size_t)sn * DD + cB + 1], vy);
        atomicAdd(&agg[(size_t)dn * DD + cB], vx);
        atomicAdd(&agg[(size_t)dn * DD + cB + 1], vy);
    }
}

// ---------------- fused node MLP (in place) ----------------
// nh = relu([node_h | agg] @ nW1 + nb1); node_h = nh @ nW2 + nb2
__global__ __launch_bounds__(256, 2) void node_kernel(
    float* __restrict__ node_h, const float* __restrict__ agg,
    const float* __restrict__ W1,   // [256,256]
    const float* __restrict__ b1,   // [256]
    const float* __restrict__ W2,   // [256,128]
    const float* __restrict__ b2)   // [128]
{
    __shared__ float sF[16][36];
    __shared__ float sW[16 * 256];
    __shared__ float sHt[256][36];
    __shared__ float s_init[HH];
    __shared__ float s_b2[DD];

    const int tid = threadIdx.x;
    const int n0 = blockIdx.x * TM;

    s_init[tid] = b1[tid];
    if (tid < DD) s_b2[tid] = b2[tid];
    __syncthreads();

    const int rg = tid >> 6;
    const int r0 = rg * 8;
    const int ct = tid & 63;
    const int c0 = ct * 4;

    float acc[8][4];
#pragma unroll
    for (int i = 0; i < 8; ++i)
#pragma unroll
        for (int j = 0; j < 4; ++j) acc[i][j] = s_init[c0 + j];

    const int lrow = tid >> 3;
    const int lkk  = (tid & 7) * 2;
    const int wkk  = tid >> 4;
    const int wc   = (tid & 15) * 16;

    for (int seg = 0; seg < 2; ++seg) {
        const float* gbase = (seg == 0 ? node_h : agg) + (size_t)(n0 + lrow) * DD;
        for (int kt = 0; kt < 8; ++kt) {
            const int kb = kt * 16;
            float2 fv = *(const float2*)(gbase + kb + lkk);
            const float* wp = W1 + (size_t)(seg * DD + kb + wkk) * HH + wc;
            float4 w0 = ((const float4*)wp)[0];
            float4 w1 = ((const float4*)wp)[1];
            float4 w2 = ((const float4*)wp)[2];
            float4 w3 = ((const float4*)wp)[3];
            __syncthreads();
            sF[lkk][lrow] = fv.x;
            sF[lkk + 1][lrow] = fv.y;
            float4* wd = (float4*)&sW[wkk * 256 + wc];
            wd[0] = w0; wd[1] = w1; wd[2] = w2; wd[3] = w3;
            __syncthreads();
#pragma unroll
            for (int kk = 0; kk < 16; ++kk) {
                float4 a0 = *(const float4*)&sF[kk][r0];
                float4 a1 = *(const float4*)&sF[kk][r0 + 4];
                float4 b  = *(const float4*)&sW[kk * 256 + c0];
                float av[8] = {a0.x, a0.y, a0.z, a0.w, a1.x, a1.y, a1.z, a1.w};
                float bv[4] = {b.x, b.y, b.z, b.w};
#pragma unroll
                for (int i = 0; i < 8; ++i)
#pragma unroll
                    for (int j = 0; j < 4; ++j)
                        acc[i][j] = fmaf(av[i], bv[j], acc[i][j]);
            }
        }
    }

#pragma unroll
    for (int j = 0; j < 4; ++j)
#pragma unroll
        for (int i = 0; i < 8; ++i)
            sHt[c0 + j][r0 + i] = fmaxf(acc[i][j], 0.0f);

    const int cB = ct * 2;
    float acc2[8][2];
#pragma unroll
    for (int i = 0; i < 8; ++i) { acc2[i][0] = s_b2[cB]; acc2[i][1] = s_b2[cB + 1]; }

    const int bkk = tid >> 3;
    const int bc  = (tid & 7) * 16;
    for (int kt = 0; kt < 8; ++kt) {
        const int kb = kt * 32;
        const float* wp = W2 + (size_t)(kb + bkk) * DD + bc;
        float4 w0 = ((const float4*)wp)[0];
        float4 w1 = ((const float4*)wp)[1];
        float4 w2 = ((const float4*)wp)[2];
        float4 w3 = ((const float4*)wp)[3];
        __syncthreads();
        float4* wd = (float4*)&sW[bkk * 128 + bc];
        wd[0] = w0; wd[1] = w1; wd[2] = w2; wd[3] = w3;
        __syncthreads();
#pragma unroll
        for (int kk = 0; kk < 32; ++kk) {
            float4 a0 = *(const float4*)&sHt[kb + kk][r0];
            float4 a1 = *(const float4*)&sHt[kb + kk][r0 + 4];
            float2 b  = *(const float2*)&sW[kk * 128 + cB];
            float av[8] = {a0.x, a0.y, a0.z, a0.w, a1.x, a1.y, a1.z, a1.w};
#pragma unroll
            for (int i = 0; i < 8; ++i) {
                acc2[i][0] = fmaf(av[i], b.x, acc2[i][0]);
                acc2[i][1] = fmaf(av[i], b.y, acc2[i][1]);
            }
        }
    }

#pragma unroll
    for (int i = 0; i < 8; ++i) {
        int n = n0 + r0 + i;
        *(float2*)&node_h[(size_t)n * DD + cB] = make_float2(acc2[i][0], acc2[i][1]);
    }
}

// ---------------- sigmoid(h @ w + b) ----------------
__global__ void score_kernel(const float* __restrict__ hmat, const float* __restrict__ w,
                             const float* __restrict__ b, float* __restrict__ out) {
    int wid = threadIdx.x >> 6;        // 4 waves per block, one row each
    int lane = threadIdx.x & 63;
    int row = blockIdx.x * 4 + wid;
    float2 v  = *(const float2*)(hmat + (size_t)row * DD + lane * 2);
    float2 wv = *(const float2*)(w + lane * 2);
    float s = v.x * wv.x + v.y * wv.y;
#pragma unroll
    for (int off = 32; off; off >>= 1) s += __shfl_down(s, off);
    if (lane == 0) out[row] = 1.0f / (1.0f + expf(-(s + b[0])));
}

extern "C" void kernel_launch(void* const* d_in, const int* in_sizes, int n_in,
                              void* d_out, int out_size, void* d_ws, size_t ws_size,
                              hipStream_t stream) {
    float* node_h = (float*)d_in[0];            // mutated in place (restored each launch)
    float* edge_h = (float*)d_in[1];            // mutated in place
    const float* qe   = (const float*)d_in[2];
    const int*   eidx = (const int*)d_in[3];
    // d_in[4] edge_type: unused
    const float* qW  = (const float*)d_in[5];
    const float* qb  = (const float*)d_in[6];
    const float* eW1 = (const float*)d_in[7];
    const float* eb1 = (const float*)d_in[8];
    const float* eW2 = (const float*)d_in[9];
    const float* eb2 = (const float*)d_in[10];
    const float* nW1 = (const float*)d_in[11];
    const float* nb1 = (const float*)d_in[12];
    const float* nW2 = (const float*)d_in[13];
    const float* nb2 = (const float*)d_in[14];
    const float* esW = (const float*)d_in[15];
    const float* esb = (const float*)d_in[16];
    const float* nsW = (const float*)d_in[17];
    const float* nsb = (const float*)d_in[18];

    float* ws  = (float*)d_ws;
    float* q   = ws;            // 128 floats
    float* qc  = ws + 256;      // 3*256 floats
    float* agg = ws + 1024;     // N*128 floats

    q_kernel<<<1, DD, 0, stream>>>(qe, qW, qb, q);
    qc_kernel<<<NL, HH, 0, stream>>>(q, eW1, eb1, qc);

    for (int l = 0; l < NL; ++l) {
        hipMemsetAsync(agg, 0, (size_t)NN * DD * sizeof(float), stream);
        edge_kernel<<<NE / TM, 256, 0, stream>>>(
            node_h, edge_h, eidx,
            eW1 + (size_t)l * 4 * DD * HH, qc + l * HH,
            eW2 + (size_t)l * HH * DD, eb2 + l * DD, agg);
        node_kernel<<<NN / TM, 256, 0, stream>>>(
            node_h, agg,
            nW1 + (size_t)l * 2 * DD * HH, nb1 + l * HH,
            nW2 + (size_t)l * HH * DD, nb2 + l * DD);
    }

    score_kernel<<<NN / 4, 256, 0, stream>>>(node_h, nsW, nsb, (float*)d_out);
    score_kernel<<<NE / 4, 256, 0, stream>>>(edge_h, esW, esb, (float*)d_out + NN);
}

// Round 3
// 3001.538 us; speedup vs baseline: 3.0591x; 3.0591x over previous
//
#include <hip/hip_runtime.h>
#include <math.h>

#define NN 100000
#define NE 640000
#define DD 128
#define HH 256
#define NL 3
#define QDIM 768
#define TM 32

#define A1P 392   // f16 pitch for [32][384] staged features (+8 pad)
#define A2P 264   // f16 pitch for [32][256] hidden

typedef _Float16 h16x8 __attribute__((ext_vector_type(8)));
typedef float f32x4 __attribute__((ext_vector_type(4)));

#define MFMA16(A, B, C) __builtin_amdgcn_mfma_f32_16x16x32_f16(A, B, C, 0, 0, 0)

__device__ __forceinline__ unsigned short f2h_bits(float f) {
    _Float16 h = (_Float16)f;                 // v_cvt_f16_f32, RTN
    return __builtin_bit_cast(unsigned short, h);
}

// ---------------- q = question_embedding @ qW + qb (fp32, tiny) ----------------
__global__ void q_kernel(const float* __restrict__ qe, const float* __restrict__ qW,
                         const float* __restrict__ qb, float* __restrict__ q) {
    int d = threadIdx.x;  // 128 threads
    float acc = qb[d];
    for (int k = 0; k < QDIM; ++k) acc = fmaf(qe[k], qW[k * DD + d], acc);
    q[d] = acc;
}

// qc[l][h] = eb1[l][h] + sum_d q[d] * eW1[l][3D + d][h]   (fp32-exact q segment)
__global__ void qc_kernel(const float* __restrict__ q, const float* __restrict__ eW1,
                          const float* __restrict__ eb1, float* __restrict__ qc) {
    int l = blockIdx.x;
    int h = threadIdx.x;  // 256 threads
    const float* W = eW1 + ((size_t)l * 4 * DD + 3 * DD) * HH;
    __shared__ float sq[DD];
    if (h < DD) sq[h] = q[h];
    __syncthreads();
    float acc = eb1[l * HH + h];
    for (int d = 0; d < DD; ++d) acc = fmaf(sq[d], W[d * HH + h], acc);
    qc[l * HH + h] = acc;
}

// ---- pack fp32 weight [l][K x Ncols] -> f16 MFMA B-fragments, hi plane + lo plane ----
// hi[lane frag] = f16(w); lo = f16(w - hi)  => hi+lo carries ~21 mantissa bits of w
__global__ void pack_kernel(const float* __restrict__ W, unsigned short* __restrict__ out,
                            int K, int Ncols, int lstride, size_t plane /*shorts*/) {
    int nct = Ncols >> 4;
    int bx = blockIdx.x;
    int l = blockIdx.y;
    int lane = threadIdx.x;
    const float* Wl = W + (size_t)l * lstride;
    int kt = bx / nct, ct = bx - kt * nct;
    int r = kt * 32 + (lane >> 4) * 8;
    int c = ct * 16 + (lane & 15);
    unsigned vh[4], vl[4];
#pragma unroll
    for (int p = 0; p < 4; ++p) {
        float x0 = Wl[(size_t)(r + 2 * p) * Ncols + c];
        float x1 = Wl[(size_t)(r + 2 * p + 1) * Ncols + c];
        _Float16 h0 = (_Float16)x0, h1 = (_Float16)x1;
        _Float16 l0 = (_Float16)(x0 - (float)h0), l1 = (_Float16)(x1 - (float)h1);
        vh[p] = (unsigned)__builtin_bit_cast(unsigned short, h0) |
                ((unsigned)__builtin_bit_cast(unsigned short, h1) << 16);
        vl[p] = (unsigned)__builtin_bit_cast(unsigned short, l0) |
                ((unsigned)__builtin_bit_cast(unsigned short, l1) << 16);
    }
    size_t off = (size_t)l * K * Ncols + ((size_t)bx * 64 + lane) * 8;
    *(uint4*)(out + off) = make_uint4(vh[0], vh[1], vh[2], vh[3]);
    *(uint4*)(out + plane + off) = make_uint4(vl[0], vl[1], vl[2], vl[3]);
}

// ---------------- fused edge MLP (f16 MFMA, split-B) + scatter ----------------
__global__ __launch_bounds__(256, 3) void edge_kernel(
    const float* __restrict__ node_h, float* __restrict__ edge_h,
    const int* __restrict__ eidx,
    const unsigned short* __restrict__ W1hi, const unsigned short* __restrict__ W1lo,
    const float* __restrict__ qc,            // [256] bias incl. q-segment
    const unsigned short* __restrict__ W2hi, const unsigned short* __restrict__ W2lo,
    const float* __restrict__ b2,            // [128]
    float* __restrict__ agg)                 // [N,128] fp32
{
    __shared__ unsigned short sA1[TM * A1P];
    __shared__ unsigned short sA2[TM * A2P];
    __shared__ int s_src[TM], s_dst[TM];
    __shared__ float s_init[HH];
    __shared__ float s_b2[DD];

    const int tid = threadIdx.x;
    const int e0 = blockIdx.x * TM;

    if (tid < TM) {
        s_src[tid] = eidx[e0 + tid];
        s_dst[tid] = eidx[NE + e0 + tid];
    }
    s_init[tid] = qc[tid];
    if (tid < DD) s_b2[tid] = b2[tid];
    __syncthreads();

    // ---- stage gathered features -> sA1 (f16, row-major, pitch A1P) ----
    {
        const int row = tid >> 3, t8 = tid & 7;
        const float* b0 = node_h + (size_t)s_src[row] * DD;
        const float* b1 = node_h + (size_t)s_dst[row] * DD;
        const float* b2p = edge_h + (size_t)(e0 + row) * DD;
#pragma unroll
        for (int i = 0; i < 12; ++i) {
            int seg = i >> 2;
            int k = (t8 + 8 * i) * 4;               // 0..380
            int klocal = k - seg * DD;
            const float* g = (seg == 0) ? b0 : (seg == 1) ? b1 : b2p;
            float4 v = *(const float4*)(g + klocal);
            uint2 p;
            p.x = (unsigned)f2h_bits(v.x) | ((unsigned)f2h_bits(v.y) << 16);
            p.y = (unsigned)f2h_bits(v.z) | ((unsigned)f2h_bits(v.w) << 16);
            *(uint2*)&sA1[row * A1P + k] = p;
        }
    }

    const int lane = tid & 63;
    const int w = tid >> 6;           // wave id: cols w*64.. (GEMM1), w*32.. (GEMM2)
    const int lrow = lane & 15;
    const int q4 = lane >> 4;

    // ---- GEMM1: [32x384] @ [384x256] -> acc[2][4] ----
    f32x4 acc[2][4];
#pragma unroll
    for (int ct = 0; ct < 4; ++ct) {
        float iv = s_init[w * 64 + ct * 16 + lrow];
        f32x4 c = {iv, iv, iv, iv};
        acc[0][ct] = c;
        acc[1][ct] = c;
    }
    __syncthreads();

    const h16x8* W1h = (const h16x8*)W1hi;
    const h16x8* W1l = (const h16x8*)W1lo;
    for (int kt = 0; kt < 12; ++kt) {
        h16x8 a0 = *(const h16x8*)&sA1[lrow * A1P + kt * 32 + q4 * 8];
        h16x8 a1 = *(const h16x8*)&sA1[(lrow + 16) * A1P + kt * 32 + q4 * 8];
#pragma unroll
        for (int ct = 0; ct < 4; ++ct) {
            h16x8 bh = W1h[(kt * 16 + w * 4 + ct) * 64 + lane];
            h16x8 bl = W1l[(kt * 16 + w * 4 + ct) * 64 + lane];
            acc[0][ct] = MFMA16(a0, bh, acc[0][ct]);
            acc[0][ct] = MFMA16(a0, bl, acc[0][ct]);
            acc[1][ct] = MFMA16(a1, bh, acc[1][ct]);
            acc[1][ct] = MFMA16(a1, bl, acc[1][ct]);
        }
    }

    // ---- relu -> f16 hidden in sA2 ----
#pragma unroll
    for (int rt = 0; rt < 2; ++rt)
#pragma unroll
        for (int ct = 0; ct < 4; ++ct)
#pragma unroll
            for (int j = 0; j < 4; ++j) {
                int hr = rt * 16 + q4 * 4 + j;
                int hc = w * 64 + ct * 16 + lrow;
                sA2[hr * A2P + hc] = f2h_bits(fmaxf(acc[rt][ct][j], 0.0f));
            }
    __syncthreads();

    // ---- GEMM2: [32x256] @ [256x128] -> acc2[2][2] ----
    f32x4 acc2[2][2];
#pragma unroll
    for (int ct = 0; ct < 2; ++ct) {
        float iv = s_b2[w * 32 + ct * 16 + lrow];
        f32x4 c = {iv, iv, iv, iv};
        acc2[0][ct] = c;
        acc2[1][ct] = c;
    }
    const h16x8* W2h = (const h16x8*)W2hi;
    const h16x8* W2l = (const h16x8*)W2lo;
    for (int kt = 0; kt < 8; ++kt) {
        h16x8 a0 = *(const h16x8*)&sA2[lrow * A2P + kt * 32 + q4 * 8];
        h16x8 a1 = *(const h16x8*)&sA2[(lrow + 16) * A2P + kt * 32 + q4 * 8];
#pragma unroll
        for (int ct = 0; ct < 2; ++ct) {
            h16x8 bh = W2h[(kt * 8 + w * 2 + ct) * 64 + lane];
            h16x8 bl = W2l[(kt * 8 + w * 2 + ct) * 64 + lane];
            acc2[0][ct] = MFMA16(a0, bh, acc2[0][ct]);
            acc2[0][ct] = MFMA16(a0, bl, acc2[0][ct]);
            acc2[1][ct] = MFMA16(a1, bh, acc2[1][ct]);
            acc2[1][ct] = MFMA16(a1, bl, acc2[1][ct]);
        }
    }

    // ---- epilogue: edge_h in place (fp32) + f32 atomic scatter ----
#pragma unroll
    for (int rt = 0; rt < 2; ++rt)
#pragma unroll
        for (int j = 0; j < 4; ++j) {
            int rr = rt * 16 + q4 * 4 + j;
            int e = e0 + rr;
            int sn = s_src[rr], dn = s_dst[rr];
#pragma unroll
            for (int ct = 0; ct < 2; ++ct) {
                int c = w * 32 + ct * 16 + lrow;
                float v = acc2[rt][ct][j];
                edge_h[(size_t)e * DD + c] = v;
                atomicAdd(&agg[(size_t)sn * DD + c], v);
                atomicAdd(&agg[(size_t)dn * DD + c], v);
            }
        }
}

// ---------------- fused node MLP (f16 MFMA, split-B, in place) ----------------
__global__ __launch_bounds__(256, 3) void node_kernel(
    float* __restrict__ node_h, const float* __restrict__ agg,
    const unsigned short* __restrict__ W1hi, const unsigned short* __restrict__ W1lo,
    const float* __restrict__ b1,            // [256]
    const unsigned short* __restrict__ W2hi, const unsigned short* __restrict__ W2lo,
    const float* __restrict__ b2)            // [128]
{
    __shared__ unsigned short sA1[TM * A2P];   // [32][256] pitch 264
    __shared__ unsigned short sA2[TM * A2P];
    __shared__ float s_init[HH];
    __shared__ float s_b2[DD];

    const int tid = threadIdx.x;
    const int n0 = blockIdx.x * TM;

    s_init[tid] = b1[tid];
    if (tid < DD) s_b2[tid] = b2[tid];

    // ---- stage [node_h | agg] -> sA1 ----
    {
        const int row = tid >> 3, t8 = tid & 7;
        const float* g0 = node_h + (size_t)(n0 + row) * DD;
        const float* g1 = agg + (size_t)(n0 + row) * DD;
#pragma unroll
        for (int i = 0; i < 8; ++i) {
            int seg = i >> 2;
            int k = (t8 + 8 * i) * 4;               // 0..252
            int klocal = k - seg * DD;
            const float* g = seg == 0 ? g0 : g1;
            float4 v = *(const float4*)(g + klocal);
            uint2 p;
            p.x = (unsigned)f2h_bits(v.x) | ((unsigned)f2h_bits(v.y) << 16);
            p.y = (unsigned)f2h_bits(v.z) | ((unsigned)f2h_bits(v.w) << 16);
            *(uint2*)&sA1[row * A2P + k] = p;
        }
    }

    const int lane = tid & 63;
    const int w = tid >> 6;
    const int lrow = lane & 15;
    const int q4 = lane >> 4;

    f32x4 acc[2][4];
#pragma unroll
    for (int ct = 0; ct < 4; ++ct) {
        float iv = s_init[w * 64 + ct * 16 + lrow];
        f32x4 c = {iv, iv, iv, iv};
        acc[0][ct] = c;
        acc[1][ct] = c;
    }
    __syncthreads();

    const h16x8* W1h = (const h16x8*)W1hi;
    const h16x8* W1l = (const h16x8*)W1lo;
    for (int kt = 0; kt < 8; ++kt) {
        h16x8 a0 = *(const h16x8*)&sA1[lrow * A2P + kt * 32 + q4 * 8];
        h16x8 a1 = *(const h16x8*)&sA1[(lrow + 16) * A2P + kt * 32 + q4 * 8];
#pragma unroll
        for (int ct = 0; ct < 4; ++ct) {
            h16x8 bh = W1h[(kt * 16 + w * 4 + ct) * 64 + lane];
            h16x8 bl = W1l[(kt * 16 + w * 4 + ct) * 64 + lane];
            acc[0][ct] = MFMA16(a0, bh, acc[0][ct]);
            acc[0][ct] = MFMA16(a0, bl, acc[0][ct]);
            acc[1][ct] = MFMA16(a1, bh, acc[1][ct]);
            acc[1][ct] = MFMA16(a1, bl, acc[1][ct]);
        }
    }

#pragma unroll
    for (int rt = 0; rt < 2; ++rt)
#pragma unroll
        for (int ct = 0; ct < 4; ++ct)
#pragma unroll
            for (int j = 0; j < 4; ++j) {
                int hr = rt * 16 + q4 * 4 + j;
                int hc = w * 64 + ct * 16 + lrow;
                sA2[hr * A2P + hc] = f2h_bits(fmaxf(acc[rt][ct][j], 0.0f));
            }
    __syncthreads();

    f32x4 acc2[2][2];
#pragma unroll
    for (int ct = 0; ct < 2; ++ct) {
        float iv = s_b2[w * 32 + ct * 16 + lrow];
        f32x4 c = {iv, iv, iv, iv};
        acc2[0][ct] = c;
        acc2[1][ct] = c;
    }
    const h16x8* W2h = (const h16x8*)W2hi;
    const h16x8* W2l = (const h16x8*)W2lo;
    for (int kt = 0; kt < 8; ++kt) {
        h16x8 a0 = *(const h16x8*)&sA2[lrow * A2P + kt * 32 + q4 * 8];
        h16x8 a1 = *(const h16x8*)&sA2[(lrow + 16) * A2P + kt * 32 + q4 * 8];
#pragma unroll
        for (int ct = 0; ct < 2; ++ct) {
            h16x8 bh = W2h[(kt * 8 + w * 2 + ct) * 64 + lane];
            h16x8 bl = W2l[(kt * 8 + w * 2 + ct) * 64 + lane];
            acc2[0][ct] = MFMA16(a0, bh, acc2[0][ct]);
            acc2[0][ct] = MFMA16(a0, bl, acc2[0][ct]);
            acc2[1][ct] = MFMA16(a1, bh, acc2[1][ct]);
            acc2[1][ct] = MFMA16(a1, bl, acc2[1][ct]);
        }
    }

#pragma unroll
    for (int rt = 0; rt < 2; ++rt)
#pragma unroll
        for (int j = 0; j < 4; ++j) {
            int rr = rt * 16 + q4 * 4 + j;
#pragma unroll
            for (int ct = 0; ct < 2; ++ct) {
                int c = w * 32 + ct * 16 + lrow;
                node_h[(size_t)(n0 + rr) * DD + c] = acc2[rt][ct][j];
            }
        }
}

// ---------------- sigmoid(h @ w + b) ----------------
__global__ void score_kernel(const float* __restrict__ hmat, const float* __restrict__ w,
                             const float* __restrict__ b, float* __restrict__ out) {
    int wid = threadIdx.x >> 6;        // 4 waves per block, one row each
    int lane = threadIdx.x & 63;
    int row = blockIdx.x * 4 + wid;
    float2 v  = *(const float2*)(hmat + (size_t)row * DD + lane * 2);
    float2 wv = *(const float2*)(w + lane * 2);
    float s = v.x * wv.x + v.y * wv.y;
#pragma unroll
    for (int off = 32; off; off >>= 1) s += __shfl_down(s, off);
    if (lane == 0) out[row] = 1.0f / (1.0f + expf(-(s + b[0])));
}

extern "C" void kernel_launch(void* const* d_in, const int* in_sizes, int n_in,
                              void* d_out, int out_size, void* d_ws, size_t ws_size,
                              hipStream_t stream) {
    float* node_h = (float*)d_in[0];            // mutated in place (restored each launch)
    float* edge_h = (float*)d_in[1];            // mutated in place
    const float* qe   = (const float*)d_in[2];
    const int*   eidx = (const int*)d_in[3];
    // d_in[4] edge_type: unused
    const float* qW  = (const float*)d_in[5];
    const float* qb  = (const float*)d_in[6];
    const float* eW1 = (const float*)d_in[7];
    const float* eb1 = (const float*)d_in[8];
    const float* eW2 = (const float*)d_in[9];
    const float* eb2 = (const float*)d_in[10];
    const float* nW1 = (const float*)d_in[11];
    const float* nb1 = (const float*)d_in[12];
    const float* nW2 = (const float*)d_in[13];
    const float* nb2 = (const float*)d_in[14];
    const float* esW = (const float*)d_in[15];
    const float* esb = (const float*)d_in[16];
    const float* nsW = (const float*)d_in[17];
    const float* nsb = (const float*)d_in[18];

    float* ws  = (float*)d_ws;
    float* q   = ws;            // 128 floats
    float* qc  = ws + 256;      // 3*256 floats
    float* agg = ws + 1024;     // N*128 floats

    // f16 weight packs (hi plane + lo plane each) live in d_out (dead until score writes).
    // Sizes in shorts: eW1p 2*3*384*256=589824, eW2p 2*3*256*128=196608,
    // nW1p 2*3*256*256=393216, nW2p 196608; total 1376256 shorts = 2.75MB < 2.96MB.
    unsigned short* packs = (unsigned short*)d_out;
    const size_t pe1 = (size_t)NL * 384 * 256;
    const size_t pe2 = (size_t)NL * 256 * 128;
    const size_t pn1 = (size_t)NL * 256 * 256;
    const size_t pn2 = (size_t)NL * 256 * 128;
    unsigned short* eW1p = packs;
    unsigned short* eW2p = eW1p + 2 * pe1;
    unsigned short* nW1p = eW2p + 2 * pe2;
    unsigned short* nW2p = nW1p + 2 * pn1;

    q_kernel<<<1, DD, 0, stream>>>(qe, qW, qb, q);
    qc_kernel<<<NL, HH, 0, stream>>>(q, eW1, eb1, qc);
    pack_kernel<<<dim3(12 * 16, NL), 64, 0, stream>>>(eW1, eW1p, 384, 256, 4 * DD * HH, pe1);
    pack_kernel<<<dim3(8 * 8, NL), 64, 0, stream>>>(eW2, eW2p, 256, 128, HH * DD, pe2);
    pack_kernel<<<dim3(8 * 16, NL), 64, 0, stream>>>(nW1, nW1p, 256, 256, 2 * DD * HH, pn1);
    pack_kernel<<<dim3(8 * 8, NL), 64, 0, stream>>>(nW2, nW2p, 256, 128, HH * DD, pn2);

    for (int l = 0; l < NL; ++l) {
        hipMemsetAsync(agg, 0, (size_t)NN * DD * sizeof(float), stream);
        edge_kernel<<<NE / TM, 256, 0, stream>>>(
            node_h, edge_h, eidx,
            eW1p + (size_t)l * 384 * 256, eW1p + pe1 + (size_t)l * 384 * 256,
            qc + l * HH,
            eW2p + (size_t)l * 256 * 128, eW2p + pe2 + (size_t)l * 256 * 128,
            eb2 + l * DD, agg);
        node_kernel<<<NN / TM, 256, 0, stream>>>(
            node_h, agg,
            nW1p + (size_t)l * 256 * 256, nW1p + pn1 + (size_t)l * 256 * 256,
            nb1 + l * HH,
            nW2p + (size_t)l * 256 * 128, nW2p + pn2 + (size_t)l * 256 * 128,
            nb2 + l * DD);
    }

    score_kernel<<<NN / 4, 256, 0, stream>>>(node_h, nsW, nsb, (float*)d_out);
    score_kernel<<<NE / 4, 256, 0, stream>>>(edge_h, esW, esb, (float*)d_out + NN);
}

// Round 4
// 3000.690 us; speedup vs baseline: 3.0599x; 1.0003x over previous
//
#include <hip/hip_runtime.h>
#include <math.h>

#define NN 100000
#define NE 640000
#define DD 128
#define HH 256
#define NL 3
#define QDIM 768
#define TM 32

#define A1P 392   // f16 pitch for [32][384] staged features (+8 pad)
#define A2P 264   // f16 pitch for [32][256] hidden

typedef _Float16 h16x8 __attribute__((ext_vector_type(8)));
typedef float f32x4 __attribute__((ext_vector_type(4)));

#define MFMA16(A, B, C) __builtin_amdgcn_mfma_f32_16x16x32_f16(A, B, C, 0, 0, 0)

__device__ __forceinline__ unsigned short f2h_bits(float f) {
    _Float16 h = (_Float16)f;                 // v_cvt_f16_f32, RTN
    return __builtin_bit_cast(unsigned short, h);
}

// ---------------- q = question_embedding @ qW + qb (fp32, tiny) ----------------
__global__ void q_kernel(const float* __restrict__ qe, const float* __restrict__ qW,
                         const float* __restrict__ qb, float* __restrict__ q) {
    int d = threadIdx.x;  // 128 threads
    float acc = qb[d];
    for (int k = 0; k < QDIM; ++k) acc = fmaf(qe[k], qW[k * DD + d], acc);
    q[d] = acc;
}

// qc[l][h] = eb1[l][h] + sum_d q[d] * eW1[l][3D + d][h]   (fp32-exact q segment)
__global__ void qc_kernel(const float* __restrict__ q, const float* __restrict__ eW1,
                          const float* __restrict__ eb1, float* __restrict__ qc) {
    int l = blockIdx.x;
    int h = threadIdx.x;  // 256 threads
    const float* W = eW1 + ((size_t)l * 4 * DD + 3 * DD) * HH;
    __shared__ float sq[DD];
    if (h < DD) sq[h] = q[h];
    __syncthreads();
    float acc = eb1[l * HH + h];
    for (int d = 0; d < DD; ++d) acc = fmaf(sq[d], W[d * HH + h], acc);
    qc[l * HH + h] = acc;
}

// ---- pack fp32 weight [l][K x Ncols] -> f16 MFMA B-fragments, hi plane + lo plane ----
__global__ void pack_kernel(const float* __restrict__ W, unsigned short* __restrict__ out,
                            int K, int Ncols, int lstride, size_t plane /*shorts*/) {
    int nct = Ncols >> 4;
    int bx = blockIdx.x;
    int l = blockIdx.y;
    int lane = threadIdx.x;
    const float* Wl = W + (size_t)l * lstride;
    int kt = bx / nct, ct = bx - kt * nct;
    int r = kt * 32 + (lane >> 4) * 8;
    int c = ct * 16 + (lane & 15);
    unsigned vh[4], vl[4];
#pragma unroll
    for (int p = 0; p < 4; ++p) {
        float x0 = Wl[(size_t)(r + 2 * p) * Ncols + c];
        float x1 = Wl[(size_t)(r + 2 * p + 1) * Ncols + c];
        _Float16 h0 = (_Float16)x0, h1 = (_Float16)x1;
        _Float16 l0 = (_Float16)(x0 - (float)h0), l1 = (_Float16)(x1 - (float)h1);
        vh[p] = (unsigned)__builtin_bit_cast(unsigned short, h0) |
                ((unsigned)__builtin_bit_cast(unsigned short, h1) << 16);
        vl[p] = (unsigned)__builtin_bit_cast(unsigned short, l0) |
                ((unsigned)__builtin_bit_cast(unsigned short, l1) << 16);
    }
    size_t off = (size_t)l * K * Ncols + ((size_t)bx * 64 + lane) * 8;
    *(uint4*)(out + off) = make_uint4(vh[0], vh[1], vh[2], vh[3]);
    *(uint4*)(out + plane + off) = make_uint4(vl[0], vl[1], vl[2], vl[3]);
}

// ---------------- CSR build: cnt -> scan -> fill ----------------
__global__ void deg_kernel(const int* __restrict__ eidx, int* __restrict__ cnt) {
    int i = blockIdx.x * 256 + threadIdx.x;
    if (i < 2 * NE) atomicAdd(&cnt[eidx[i]], 1);
}

#define SCAN_T 1024
__global__ void scan_kernel(const int* __restrict__ cnt, int* __restrict__ offsets,
                            int* __restrict__ cursor) {
    __shared__ int s[SCAN_T];
    int t = threadIdx.x;
    const int chunk = (NN + SCAN_T - 1) / SCAN_T;  // 98
    int lo = t * chunk, hi = lo + chunk; if (hi > NN) hi = NN;
    int sum = 0;
    for (int i = lo; i < hi; ++i) sum += cnt[i];
    s[t] = sum;
    __syncthreads();
    for (int off = 1; off < SCAN_T; off <<= 1) {
        int v = (t >= off) ? s[t - off] : 0;
        __syncthreads();
        s[t] += v;
        __syncthreads();
    }
    int run = (t == 0) ? 0 : s[t - 1];
    for (int i = lo; i < hi; ++i) {
        int c = cnt[i];
        offsets[i] = run;
        cursor[i] = run;
        run += c;
    }
    if (t == SCAN_T - 1) offsets[NN] = run;
}

__global__ void fill_kernel(const int* __restrict__ eidx, int* __restrict__ cursor,
                            int* __restrict__ inc) {
    int i = blockIdx.x * 256 + threadIdx.x;
    if (i < 2 * NE) {
        int e = (i < NE) ? i : i - NE;
        int pos = atomicAdd(&cursor[eidx[i]], 1);
        inc[pos] = e;
    }
}

// ---------------- fused edge MLP (f16 MFMA, split-B), no scatter ----------------
__global__ __launch_bounds__(256, 3) void edge_kernel(
    const float* __restrict__ node_h, float* __restrict__ edge_h,
    const int* __restrict__ eidx,
    const unsigned short* __restrict__ W1hi, const unsigned short* __restrict__ W1lo,
    const float* __restrict__ qc,            // [256] bias incl. q-segment
    const unsigned short* __restrict__ W2hi, const unsigned short* __restrict__ W2lo,
    const float* __restrict__ b2)            // [128]
{
    __shared__ unsigned short sA1[TM * A1P];
    __shared__ unsigned short sA2[TM * A2P];
    __shared__ int s_src[TM], s_dst[TM];
    __shared__ float s_init[HH];
    __shared__ float s_b2[DD];

    const int tid = threadIdx.x;
    const int e0 = blockIdx.x * TM;

    if (tid < TM) {
        s_src[tid] = eidx[e0 + tid];
        s_dst[tid] = eidx[NE + e0 + tid];
    }
    s_init[tid] = qc[tid];
    if (tid < DD) s_b2[tid] = b2[tid];
    __syncthreads();

    // ---- stage gathered features -> sA1 (f16, row-major, pitch A1P) ----
    {
        const int row = tid >> 3, t8 = tid & 7;
        const float* b0 = node_h + (size_t)s_src[row] * DD;
        const float* b1 = node_h + (size_t)s_dst[row] * DD;
        const float* b2p = edge_h + (size_t)(e0 + row) * DD;
#pragma unroll
        for (int i = 0; i < 12; ++i) {
            int seg = i >> 2;
            int k = (t8 + 8 * i) * 4;               // 0..380
            int klocal = k - seg * DD;
            const float* g = (seg == 0) ? b0 : (seg == 1) ? b1 : b2p;
            float4 v = *(const float4*)(g + klocal);
            uint2 p;
            p.x = (unsigned)f2h_bits(v.x) | ((unsigned)f2h_bits(v.y) << 16);
            p.y = (unsigned)f2h_bits(v.z) | ((unsigned)f2h_bits(v.w) << 16);
            *(uint2*)&sA1[row * A1P + k] = p;
        }
    }

    const int lane = tid & 63;
    const int w = tid >> 6;           // wave id: cols w*64.. (GEMM1), w*32.. (GEMM2)
    const int lrow = lane & 15;
    const int q4 = lane >> 4;

    // ---- GEMM1: [32x384] @ [384x256] -> acc[2][4] ----
    f32x4 acc[2][4];
#pragma unroll
    for (int ct = 0; ct < 4; ++ct) {
        float iv = s_init[w * 64 + ct * 16 + lrow];
        f32x4 c = {iv, iv, iv, iv};
        acc[0][ct] = c;
        acc[1][ct] = c;
    }
    __syncthreads();

    const h16x8* W1h = (const h16x8*)W1hi;
    const h16x8* W1l = (const h16x8*)W1lo;
    for (int kt = 0; kt < 12; ++kt) {
        h16x8 a0 = *(const h16x8*)&sA1[lrow * A1P + kt * 32 + q4 * 8];
        h16x8 a1 = *(const h16x8*)&sA1[(lrow + 16) * A1P + kt * 32 + q4 * 8];
#pragma unroll
        for (int ct = 0; ct < 4; ++ct) {
            h16x8 bh = W1h[(kt * 16 + w * 4 + ct) * 64 + lane];
            h16x8 bl = W1l[(kt * 16 + w * 4 + ct) * 64 + lane];
            acc[0][ct] = MFMA16(a0, bh, acc[0][ct]);
            acc[0][ct] = MFMA16(a0, bl, acc[0][ct]);
            acc[1][ct] = MFMA16(a1, bh, acc[1][ct]);
            acc[1][ct] = MFMA16(a1, bl, acc[1][ct]);
        }
    }

    // ---- relu -> f16 hidden in sA2 ----
#pragma unroll
    for (int rt = 0; rt < 2; ++rt)
#pragma unroll
        for (int ct = 0; ct < 4; ++ct)
#pragma unroll
            for (int j = 0; j < 4; ++j) {
                int hr = rt * 16 + q4 * 4 + j;
                int hc = w * 64 + ct * 16 + lrow;
                sA2[hr * A2P + hc] = f2h_bits(fmaxf(acc[rt][ct][j], 0.0f));
            }
    __syncthreads();

    // ---- GEMM2: [32x256] @ [256x128] -> acc2[2][2] ----
    f32x4 acc2[2][2];
#pragma unroll
    for (int ct = 0; ct < 2; ++ct) {
        float iv = s_b2[w * 32 + ct * 16 + lrow];
        f32x4 c = {iv, iv, iv, iv};
        acc2[0][ct] = c;
        acc2[1][ct] = c;
    }
    const h16x8* W2h = (const h16x8*)W2hi;
    const h16x8* W2l = (const h16x8*)W2lo;
    for (int kt = 0; kt < 8; ++kt) {
        h16x8 a0 = *(const h16x8*)&sA2[lrow * A2P + kt * 32 + q4 * 8];
        h16x8 a1 = *(const h16x8*)&sA2[(lrow + 16) * A2P + kt * 32 + q4 * 8];
#pragma unroll
        for (int ct = 0; ct < 2; ++ct) {
            h16x8 bh = W2h[(kt * 8 + w * 2 + ct) * 64 + lane];
            h16x8 bl = W2l[(kt * 8 + w * 2 + ct) * 64 + lane];
            acc2[0][ct] = MFMA16(a0, bh, acc2[0][ct]);
            acc2[0][ct] = MFMA16(a0, bl, acc2[0][ct]);
            acc2[1][ct] = MFMA16(a1, bh, acc2[1][ct]);
            acc2[1][ct] = MFMA16(a1, bl, acc2[1][ct]);
        }
    }

    // ---- epilogue: edge_h in place (fp32) ----
#pragma unroll
    for (int rt = 0; rt < 2; ++rt)
#pragma unroll
        for (int j = 0; j < 4; ++j) {
            int rr = rt * 16 + q4 * 4 + j;
            int e = e0 + rr;
#pragma unroll
            for (int ct = 0; ct < 2; ++ct) {
                int c = w * 32 + ct * 16 + lrow;
                edge_h[(size_t)e * DD + c] = acc2[rt][ct][j];
            }
        }
}

// ---------------- fused node MLP (f16 MFMA, split-B) with CSR pull-aggregation ----
__global__ __launch_bounds__(256, 3) void node_kernel(
    float* __restrict__ node_h, const float* __restrict__ edge_h,
    const int* __restrict__ offsets, const int* __restrict__ inc,
    const unsigned short* __restrict__ W1hi, const unsigned short* __restrict__ W1lo,
    const float* __restrict__ b1,            // [256]
    const unsigned short* __restrict__ W2hi, const unsigned short* __restrict__ W2lo,
    const float* __restrict__ b2)            // [128]
{
    __shared__ unsigned short sA1[TM * A2P];   // [32][256] pitch 264
    __shared__ unsigned short sA2[TM * A2P];
    __shared__ float s_init[HH];
    __shared__ float s_b2[DD];

    const int tid = threadIdx.x;
    const int n0 = blockIdx.x * TM;

    s_init[tid] = b1[tid];
    if (tid < DD) s_b2[tid] = b2[tid];

    const int row = tid >> 3, t8 = tid & 7;

    // ---- stage node_h -> sA1 cols [0,128) ----
    {
        const float* g0 = node_h + (size_t)(n0 + row) * DD;
#pragma unroll
        for (int i = 0; i < 4; ++i) {
            int k = (t8 + 8 * i) * 4;               // 0..124
            float4 v = *(const float4*)(g0 + k);
            uint2 p;
            p.x = (unsigned)f2h_bits(v.x) | ((unsigned)f2h_bits(v.y) << 16);
            p.y = (unsigned)f2h_bits(v.z) | ((unsigned)f2h_bits(v.w) << 16);
            *(uint2*)&sA1[row * A2P + k] = p;
        }
    }

    // ---- pull-aggregate incident edge rows -> fp32 regs -> sA1 cols [128,256) ----
    {
        int n = n0 + row;
        int k0 = offsets[n], k1 = offsets[n + 1];
        float a[16];
#pragma unroll
        for (int j = 0; j < 16; ++j) a[j] = 0.0f;
        for (int k = k0; k < k1; ++k) {
            int e = inc[k];
            const float* er = edge_h + (size_t)e * DD;
#pragma unroll
            for (int j = 0; j < 4; ++j) {
                float4 v = *(const float4*)(er + j * 32 + t8 * 4);
                a[j * 4 + 0] += v.x;
                a[j * 4 + 1] += v.y;
                a[j * 4 + 2] += v.z;
                a[j * 4 + 3] += v.w;
            }
        }
#pragma unroll
        for (int j = 0; j < 4; ++j) {
            int c = 128 + j * 32 + t8 * 4;
            uint2 p;
            p.x = (unsigned)f2h_bits(a[j * 4 + 0]) | ((unsigned)f2h_bits(a[j * 4 + 1]) << 16);
            p.y = (unsigned)f2h_bits(a[j * 4 + 2]) | ((unsigned)f2h_bits(a[j * 4 + 3]) << 16);
            *(uint2*)&sA1[row * A2P + c] = p;
        }
    }

    const int lane = tid & 63;
    const int w = tid >> 6;
    const int lrow = lane & 15;
    const int q4 = lane >> 4;

    f32x4 acc[2][4];
#pragma unroll
    for (int ct = 0; ct < 4; ++ct) {
        float iv = s_init[w * 64 + ct * 16 + lrow];
        f32x4 c = {iv, iv, iv, iv};
        acc[0][ct] = c;
        acc[1][ct] = c;
    }
    __syncthreads();

    const h16x8* W1h = (const h16x8*)W1hi;
    const h16x8* W1l = (const h16x8*)W1lo;
    for (int kt = 0; kt < 8; ++kt) {
        h16x8 a0 = *(const h16x8*)&sA1[lrow * A2P + kt * 32 + q4 * 8];
        h16x8 a1 = *(const h16x8*)&sA1[(lrow + 16) * A2P + kt * 32 + q4 * 8];
#pragma unroll
        for (int ct = 0; ct < 4; ++ct) {
            h16x8 bh = W1h[(kt * 16 + w * 4 + ct) * 64 + lane];
            h16x8 bl = W1l[(kt * 16 + w * 4 + ct) * 64 + lane];
            acc[0][ct] = MFMA16(a0, bh, acc[0][ct]);
            acc[0][ct] = MFMA16(a0, bl, acc[0][ct]);
            acc[1][ct] = MFMA16(a1, bh, acc[1][ct]);
            acc[1][ct] = MFMA16(a1, bl, acc[1][ct]);
        }
    }

#pragma unroll
    for (int rt = 0; rt < 2; ++rt)
#pragma unroll
        for (int ct = 0; ct < 4; ++ct)
#pragma unroll
            for (int j = 0; j < 4; ++j) {
                int hr = rt * 16 + q4 * 4 + j;
                int hc = w * 64 + ct * 16 + lrow;
                sA2[hr * A2P + hc] = f2h_bits(fmaxf(acc[rt][ct][j], 0.0f));
            }
    __syncthreads();

    f32x4 acc2[2][2];
#pragma unroll
    for (int ct = 0; ct < 2; ++ct) {
        float iv = s_b2[w * 32 + ct * 16 + lrow];
        f32x4 c = {iv, iv, iv, iv};
        acc2[0][ct] = c;
        acc2[1][ct] = c;
    }
    const h16x8* W2h = (const h16x8*)W2hi;
    const h16x8* W2l = (const h16x8*)W2lo;
    for (int kt = 0; kt < 8; ++kt) {
        h16x8 a0 = *(const h16x8*)&sA2[lrow * A2P + kt * 32 + q4 * 8];
        h16x8 a1 = *(const h16x8*)&sA2[(lrow + 16) * A2P + kt * 32 + q4 * 8];
#pragma unroll
        for (int ct = 0; ct < 2; ++ct) {
            h16x8 bh = W2h[(kt * 8 + w * 2 + ct) * 64 + lane];
            h16x8 bl = W2l[(kt * 8 + w * 2 + ct) * 64 + lane];
            acc2[0][ct] = MFMA16(a0, bh, acc2[0][ct]);
            acc2[0][ct] = MFMA16(a0, bl, acc2[0][ct]);
            acc2[1][ct] = MFMA16(a1, bh, acc2[1][ct]);
            acc2[1][ct] = MFMA16(a1, bl, acc2[1][ct]);
        }
    }

#pragma unroll
    for (int rt = 0; rt < 2; ++rt)
#pragma unroll
        for (int j = 0; j < 4; ++j) {
            int rr = rt * 16 + q4 * 4 + j;
#pragma unroll
            for (int ct = 0; ct < 2; ++ct) {
                int c = w * 32 + ct * 16 + lrow;
                node_h[(size_t)(n0 + rr) * DD + c] = acc2[rt][ct][j];
            }
        }
}

// ---------------- sigmoid(h @ w + b) ----------------
__global__ void score_kernel(const float* __restrict__ hmat, const float* __restrict__ w,
                             const float* __restrict__ b, float* __restrict__ out) {
    int wid = threadIdx.x >> 6;        // 4 waves per block, one row each
    int lane = threadIdx.x & 63;
    int row = blockIdx.x * 4 + wid;
    float2 v  = *(const float2*)(hmat + (size_t)row * DD + lane * 2);
    float2 wv = *(const float2*)(w + lane * 2);
    float s = v.x * wv.x + v.y * wv.y;
#pragma unroll
    for (int off = 32; off; off >>= 1) s += __shfl_down(s, off);
    if (lane == 0) out[row] = 1.0f / (1.0f + expf(-(s + b[0])));
}

extern "C" void kernel_launch(void* const* d_in, const int* in_sizes, int n_in,
                              void* d_out, int out_size, void* d_ws, size_t ws_size,
                              hipStream_t stream) {
    float* node_h = (float*)d_in[0];            // mutated in place (restored each launch)
    float* edge_h = (float*)d_in[1];            // mutated in place
    const float* qe   = (const float*)d_in[2];
    const int*   eidx = (const int*)d_in[3];
    // d_in[4] edge_type: unused
    const float* qW  = (const float*)d_in[5];
    const float* qb  = (const float*)d_in[6];
    const float* eW1 = (const float*)d_in[7];
    const float* eb1 = (const float*)d_in[8];
    const float* eW2 = (const float*)d_in[9];
    const float* eb2 = (const float*)d_in[10];
    const float* nW1 = (const float*)d_in[11];
    const float* nb1 = (const float*)d_in[12];
    const float* nW2 = (const float*)d_in[13];
    const float* nb2 = (const float*)d_in[14];
    const float* esW = (const float*)d_in[15];
    const float* esb = (const float*)d_in[16];
    const float* nsW = (const float*)d_in[17];
    const float* nsb = (const float*)d_in[18];

    float* ws  = (float*)d_ws;
    float* q   = ws;            // 128 floats
    float* qc  = ws + 256;      // 3*256 floats
    int* cnt     = (int*)(ws + 1024);   // NN
    int* cursor  = cnt + NN;            // NN
    int* offsets = cursor + NN;         // NN+1
    int* inc     = offsets + NN + 1;    // 2*NE   (total ~6.3 MB)

    // f16 weight packs (hi+lo planes) live in d_out (dead until score writes).
    unsigned short* packs = (unsigned short*)d_out;
    const size_t pe1 = (size_t)NL * 384 * 256;
    const size_t pe2 = (size_t)NL * 256 * 128;
    const size_t pn1 = (size_t)NL * 256 * 256;
    const size_t pn2 = (size_t)NL * 256 * 128;
    unsigned short* eW1p = packs;
    unsigned short* eW2p = eW1p + 2 * pe1;
    unsigned short* nW1p = eW2p + 2 * pe2;
    unsigned short* nW2p = nW1p + 2 * pn1;

    q_kernel<<<1, DD, 0, stream>>>(qe, qW, qb, q);
    qc_kernel<<<NL, HH, 0, stream>>>(q, eW1, eb1, qc);
    pack_kernel<<<dim3(12 * 16, NL), 64, 0, stream>>>(eW1, eW1p, 384, 256, 4 * DD * HH, pe1);
    pack_kernel<<<dim3(8 * 8, NL), 64, 0, stream>>>(eW2, eW2p, 256, 128, HH * DD, pe2);
    pack_kernel<<<dim3(8 * 16, NL), 64, 0, stream>>>(nW1, nW1p, 256, 256, 2 * DD * HH, pn1);
    pack_kernel<<<dim3(8 * 8, NL), 64, 0, stream>>>(nW2, nW2p, 256, 128, HH * DD, pn2);

    // ---- CSR incidence build (once; edge_index is layer-invariant) ----
    hipMemsetAsync(cnt, 0, NN * sizeof(int), stream);
    deg_kernel<<<(2 * NE + 255) / 256, 256, 0, stream>>>(eidx, cnt);
    scan_kernel<<<1, SCAN_T, 0, stream>>>(cnt, offsets, cursor);
    fill_kernel<<<(2 * NE + 255) / 256, 256, 0, stream>>>(eidx, cursor, inc);

    for (int l = 0; l < NL; ++l) {
        edge_kernel<<<NE / TM, 256, 0, stream>>>(
            node_h, edge_h, eidx,
            eW1p + (size_t)l * 384 * 256, eW1p + pe1 + (size_t)l * 384 * 256,
            qc + l * HH,
            eW2p + (size_t)l * 256 * 128, eW2p + pe2 + (size_t)l * 256 * 128,
            eb2 + l * DD);
        node_kernel<<<NN / TM, 256, 0, stream>>>(
            node_h, edge_h, offsets, inc,
            nW1p + (size_t)l * 256 * 256, nW1p + pn1 + (size_t)l * 256 * 256,
            nb1 + l * HH,
            nW2p + (size_t)l * 256 * 128, nW2p + pn2 + (size_t)l * 256 * 128,
            nb2 + l * DD);
    }

    score_kernel<<<NN / 4, 256, 0, stream>>>(node_h, nsW, nsb, (float*)d_out);
    score_kernel<<<NE / 4, 256, 0, stream>>>(edge_h, esW, esb, (float*)d_out + NN);
}